// Round 5
// baseline (632.565 us; speedup 1.0000x reference)
//
#include <hip/hip_runtime.h>

#define NN 2048
#define CC 128
#define CPC 16
#define HH 8
#define DD 16
#define WHALF 64

__device__ __forceinline__ float sigf(float x){ return 1.0f/(1.0f+__expf(-x)); }

// Core: C[m] = (A*diag(scale)?) @ Wm for up to 2 weight mats sharing A.
// Block covers RPT*8 rows x 128 cols; 256 threads; thread = (tr=t>>5 row slot, tc=t&31 col*4).
template<int K, int RPT, int NM>
__device__ __forceinline__ void gemm_core(const float* __restrict__ Arows,
                                          const float* __restrict__ scale,
                                          const float* __restrict__ W0,
                                          const float* __restrict__ W1,
                                          int ldw, int colBase,
                                          float acc[NM][RPT][4], float* As){
  const int t = threadIdx.x;
  constexpr int ROWS = RPT*8;
  const int nv = ROWS*K/4;
  for (int i=t;i<nv;i+=256){
    float4 v = ((const float4*)Arows)[i];
    if (scale){
      int kk = (i*4)&(K-1);
      v.x*=scale[kk]; v.y*=scale[kk+1]; v.z*=scale[kk+2]; v.w*=scale[kk+3];
    }
    ((float4*)As)[i]=v;
  }
  __syncthreads();
  const int tr = t>>5;
  const int col = colBase + (t&31)*4;
  #pragma unroll
  for(int m=0;m<NM;m++)
    #pragma unroll
    for(int r=0;r<RPT;r++){ acc[m][r][0]=0;acc[m][r][1]=0;acc[m][r][2]=0;acc[m][r][3]=0; }
  #pragma unroll 4
  for (int k=0;k<K;k++){
    float a[RPT];
    #pragma unroll
    for (int r=0;r<RPT;r++) a[r]=As[(tr*RPT+r)*K+k];   // 2-addr broadcast per wave: free
    {
      float4 w = *(const float4*)(W0 + (size_t)k*ldw + col);
      #pragma unroll
      for (int r=0;r<RPT;r++){acc[0][r][0]+=a[r]*w.x;acc[0][r][1]+=a[r]*w.y;acc[0][r][2]+=a[r]*w.z;acc[0][r][3]+=a[r]*w.w;}
    }
    if constexpr (NM>1){
      float4 w = *(const float4*)(W1 + (size_t)k*ldw + col);
      #pragma unroll
      for (int r=0;r<RPT;r++){acc[1][r][0]+=a[r]*w.x;acc[1][r][1]+=a[r]*w.y;acc[1][r][2]+=a[r]*w.z;acc[1][r][3]+=a[r]*w.w;}
    }
  }
}

// Fused pre-attention kernel. blockIdx.y selects:
//  y=0: sg_og = sigmoid(s@og_w+og_b), sg_tg = sigmoid(s@tg_w+tg_b)   (raw s)
//  y=1: a_att = sigmoid(sn@ada_gw+ada_gb)*LN(a) + sn@ada_sw, sn=LN(s)*ada_sc
//  y=2: tcond = same with t_* params
__global__ __launch_bounds__(256) void k_pre(
    const float* __restrict__ a_in, const float* __restrict__ s_in,
    const float* __restrict__ ada_sc, const float* __restrict__ ada_gw,
    const float* __restrict__ ada_gb, const float* __restrict__ ada_sw,
    const float* __restrict__ t_sc, const float* __restrict__ t_gw,
    const float* __restrict__ t_gb, const float* __restrict__ t_sw,
    const float* __restrict__ og_w, const float* __restrict__ og_b,
    const float* __restrict__ tg_w, const float* __restrict__ tg_b,
    float* __restrict__ sg_og, float* __restrict__ sg_tg,
    float* __restrict__ a_att, float* __restrict__ tcond)
{
  __shared__ float As[8*CC];
  __shared__ float Ls[8*CC];
  const int y = blockIdx.y;
  const int row0 = blockIdx.x*8;
  const int t = threadIdx.x;
  const int tr = t>>5, col = (t&31)*4;
  {
    float4 v = *(const float4*)(s_in + (size_t)(row0+tr)*CC + col);
    if (y==0){
      *(float4*)(As + t*4) = v;
    } else {
      float s1 = v.x+v.y+v.z+v.w;
      float s2 = v.x*v.x+v.y*v.y+v.z*v.z+v.w*v.w;
      #pragma unroll
      for (int m=16;m;m>>=1){ s1+=__shfl_xor(s1,m); s2+=__shfl_xor(s2,m); }
      float mean=s1*(1.0f/CC), var=s2*(1.0f/CC)-mean*mean, inv=rsqrtf(var+1e-5f);
      const float* sc = (y==1)? ada_sc : t_sc;
      float4 scv = *(const float4*)(sc+col);
      float4 o; o.x=(v.x-mean)*inv*scv.x; o.y=(v.y-mean)*inv*scv.y;
                o.z=(v.z-mean)*inv*scv.z; o.w=(v.w-mean)*inv*scv.w;
      *(float4*)(As + t*4) = o;
      float4 av = *(const float4*)(a_in + (size_t)(row0+tr)*CC + col);
      float a1 = av.x+av.y+av.z+av.w;
      float a2 = av.x*av.x+av.y*av.y+av.z*av.z+av.w*av.w;
      #pragma unroll
      for (int m=16;m;m>>=1){ a1+=__shfl_xor(a1,m); a2+=__shfl_xor(a2,m); }
      float am=a1*(1.0f/CC), avr=a2*(1.0f/CC)-am*am, ai=rsqrtf(avr+1e-5f);
      float4 la; la.x=(av.x-am)*ai; la.y=(av.y-am)*ai;
                 la.z=(av.z-am)*ai; la.w=(av.w-am)*ai;
      *(float4*)(Ls + t*4) = la;
    }
  }
  __syncthreads();
  const float* W0 = (y==0)? og_w : ((y==1)? ada_gw : t_gw);
  const float* W1 = (y==0)? tg_w : ((y==1)? ada_sw : t_sw);
  float acc0[4]={0,0,0,0}, acc1[4]={0,0,0,0};
  #pragma unroll 4
  for (int k=0;k<CC;k++){
    float a = As[tr*CC+k];
    float4 w0 = *(const float4*)(W0 + (size_t)k*CC + col);
    float4 w1 = *(const float4*)(W1 + (size_t)k*CC + col);
    acc0[0]+=a*w0.x; acc0[1]+=a*w0.y; acc0[2]+=a*w0.z; acc0[3]+=a*w0.w;
    acc1[0]+=a*w1.x; acc1[1]+=a*w1.y; acc1[2]+=a*w1.z; acc1[3]+=a*w1.w;
  }
  const size_t off = (size_t)(row0+tr)*CC + col;
  if (y==0){
    float4 b0 = *(const float4*)(og_b+col);
    float4 b1 = *(const float4*)(tg_b+col);
    float4 o0 = {sigf(acc0[0]+b0.x),sigf(acc0[1]+b0.y),sigf(acc0[2]+b0.z),sigf(acc0[3]+b0.w)};
    float4 o1 = {sigf(acc1[0]+b1.x),sigf(acc1[1]+b1.y),sigf(acc1[2]+b1.z),sigf(acc1[3]+b1.w)};
    *(float4*)(sg_og+off)=o0; *(float4*)(sg_tg+off)=o1;
  } else {
    const float* gbp = (y==1)? ada_gb : t_gb;
    float4 gb = *(const float4*)(gbp+col);
    float4 la = *(const float4*)(Ls + t*4);
    float4 o;
    o.x = sigf(acc0[0]+gb.x)*la.x + acc1[0];
    o.y = sigf(acc0[1]+gb.y)*la.y + acc1[1];
    o.z = sigf(acc0[2]+gb.z)*la.z + acc1[2];
    o.w = sigf(acc0[3]+gb.w)*la.w + acc1[3];
    float* dst = (y==1)? a_att : tcond;
    *(float4*)(dst+off)=o;
  }
}

// Mid stage: qkv/g projections and SwiGLU in ONE launch (all depend only on k_pre).
//  y=0: qb,kb = a_att @ wq, a_att @ wk
//  y=1: vb,gg = a_att @ wv, a_att @ wg + bg   (gg pre-sigmoid)
//  y=2: hid[:,0:128]   = silu(tcond@sw_w)*(tcond@hd_w), cols 0..127
//  y=3: hid[:,128:256] = same, cols 128..255
__global__ __launch_bounds__(256) void k_mid(
    const float* __restrict__ a_att, const float* __restrict__ tcond,
    const float* __restrict__ wq, const float* __restrict__ wk,
    const float* __restrict__ wv, const float* __restrict__ wg,
    const float* __restrict__ bg,
    const float* __restrict__ sw_w, const float* __restrict__ hd_w,
    float* __restrict__ qb, float* __restrict__ kb,
    float* __restrict__ vb, float* __restrict__ gg,
    float* __restrict__ hid)
{
  __shared__ float As[16*128];
  float acc[2][2][4];
  const int y = blockIdx.y;
  const int row0 = blockIdx.x*16;
  const int t = threadIdx.x;
  const int col4 = (t&31)*4;
  if (y < 2){
    const float* W0 = y ? wv : wq;
    const float* W1 = y ? wg : wk;
    gemm_core<128,2,2>(a_att + (size_t)row0*CC, nullptr, W0, W1, 128, 0, acc, As);
    float* O0 = y ? vb : qb;
    float* O1 = y ? gg : kb;
    float4 b1 = {0,0,0,0};
    if (y) b1 = *(const float4*)(bg+col4);
    #pragma unroll
    for (int r=0;r<2;r++){
      const int row = row0 + (t>>5)*2 + r;
      float4 o0 = {acc[0][r][0],acc[0][r][1],acc[0][r][2],acc[0][r][3]};
      float4 o1 = {acc[1][r][0]+b1.x,acc[1][r][1]+b1.y,acc[1][r][2]+b1.z,acc[1][r][3]+b1.w};
      *(float4*)(O0 + (size_t)row*CC + col4) = o0;
      *(float4*)(O1 + (size_t)row*CC + col4) = o1;
    }
  } else {
    const int cb = (y-2)*128;
    gemm_core<128,2,2>(tcond + (size_t)row0*CC, nullptr, sw_w, hd_w, 256, cb, acc, As);
    #pragma unroll
    for (int r=0;r<2;r++){
      const int row = row0 + (t>>5)*2 + r;
      float4 o;
      o.x = acc[0][r][0]*sigf(acc[0][r][0])*acc[1][r][0];
      o.y = acc[0][r][1]*sigf(acc[0][r][1])*acc[1][r][1];
      o.z = acc[0][r][2]*sigf(acc[0][r][2])*acc[1][r][2];
      o.w = acc[0][r][3]*sigf(acc[0][r][3])*acc[1][r][3];
      *(float4*)(hid + (size_t)row*256 + cb + col4) = o;
    }
  }
}

// Windowed attention with pair bias. One block per query row i. 256 threads.
// Phase A: pair LN once into LDS (129 threads). Phase B: scores with 256
// threads = 2 head-groups x 128 j (each thread loads only its 4 heads'
// K-slices; pair LN NOT recomputed). Softmax + 2-way PV as proven.
__global__ __launch_bounds__(256) void attn_win(const float* __restrict__ q,
    const float* __restrict__ k, const float* __restrict__ v,
    const float* __restrict__ g, const float* __restrict__ pair,
    const float* __restrict__ pls, const float* __restrict__ plb,
    const float* __restrict__ w_pair, const float* __restrict__ mask,
    float* __restrict__ o_out) {
  __shared__ __align__(16) float qs[CC];
  __shared__ float sc[HH][132];
  __shared__ float wp[CPC][HH];
  __shared__ float plss[CPC], plbs[CPC];
  __shared__ float inv_sum[HH];
  __shared__ float pa[256];
  __shared__ float pvs[129][CPC+1];   // +1 pad: 2-way bank alias only (free)
  __shared__ float mterm[132];
  const int i = blockIdx.x;
  const int t = threadIdx.x;
  if (t < CC) qs[t] = q[(size_t)i*CC + t] * 0.25f;   // D^-0.5 = 1/4
  if (t < CPC*HH) wp[t>>3][t&7] = w_pair[t];         // [CP][H] row-major
  if (t >= 128 && t < 128+CPC){ plss[t-128]=pls[t-128]; plbs[t-128]=plb[t-128]; }
  __syncthreads();
  const int jlo = (i-WHALF > 0) ? i-WHALF : 0;
  const int jhi = (i+WHALF < NN-1) ? i+WHALF : NN-1;
  const int nj = jhi - jlo + 1;      // 65..129
  // Phase A: LN of pair rows -> pvs, mask term -> mterm (each j once)
  for (int jj = t; jj < nj; jj += 256){
    const int j = jlo + jj;
    float pv[CPC]; float s=0.f, sq=0.f;
    const float4* pp4 = (const float4*)(pair + ((size_t)i*NN + j)*CPC);
    #pragma unroll
    for (int c4=0;c4<CPC/4;c4++){
      float4 x4 = pp4[c4];
      pv[c4*4]=x4.x; pv[c4*4+1]=x4.y; pv[c4*4+2]=x4.z; pv[c4*4+3]=x4.w;
      s += x4.x+x4.y+x4.z+x4.w;
      sq += x4.x*x4.x+x4.y*x4.y+x4.z*x4.z+x4.w*x4.w;
    }
    float mean = s*(1.0f/CPC);
    float var  = sq*(1.0f/CPC)-mean*mean;
    float inv  = rsqrtf(var+1e-5f);
    #pragma unroll
    for (int c=0;c<CPC;c++) pvs[jj][c] = (pv[c]-mean)*inv*plss[c] + plbs[c];
    mterm[jj] = 1e9f*(mask[j]-1.0f);
  }
  __syncthreads();
  // Phase B: scores, 2 head-groups x 128 j-threads
  {
    const int tt = t & 127, grp = t>>7;
    const float4* qs4 = (const float4*)qs;
    for (int jj = tt; jj < nj; jj += 128){
      const int j = jlo + jj;
      const float4* kr4 = (const float4*)(k + (size_t)j*CC);
      float pv[CPC];
      #pragma unroll
      for (int c=0;c<CPC;c++) pv[c] = pvs[jj][c];
      float mt = mterm[jj];
      #pragma unroll
      for (int hh=0;hh<4;hh++){
        const int h = grp*4 + hh;
        float bias = 0.f;
        #pragma unroll
        for (int c=0;c<CPC;c++) bias += pv[c]*wp[c][h];
        float d = 0.f;
        #pragma unroll
        for (int w=0;w<4;w++){
          float4 kk = kr4[h*4+w];
          float4 qq = qs4[h*4+w];
          d += kk.x*qq.x + kk.y*qq.y + kk.z*qq.z + kk.w*qq.w;
        }
        sc[h][jj] = d + bias + mt;
      }
    }
  }
  __syncthreads();
  { // per-head softmax: 8 groups of 32 lanes
    const int h = t >> 5;
    const int l = t & 31;
    float m = -1e30f;
    for (int jj=l; jj<nj; jj+=32) m = fmaxf(m, sc[h][jj]);
    #pragma unroll
    for (int mm=16;mm;mm>>=1) m = fmaxf(m, __shfl_xor(m,mm));
    float ss = 0.f;
    for (int jj=l; jj<nj; jj+=32){ float e=__expf(sc[h][jj]-m); sc[h][jj]=e; ss+=e; }
    #pragma unroll
    for (int mm=16;mm;mm>>=1) ss += __shfl_xor(ss,mm);
    if (l==0) inv_sum[h] = 1.0f/ss;
  }
  __syncthreads();
  { // PV: thread -> (col c, j-half), then combine halves through LDS
    const int c = t & 127, half = t>>7;
    const int h = c >> 4;
    float acc = 0.f;
    for (int jj=half; jj<nj; jj+=2)
      acc += sc[h][jj] * v[(size_t)(jlo+jj)*CC + c];
    pa[t] = acc;
    __syncthreads();
    if (t < CC){
      float gate = sigf(g[(size_t)i*CC + t]);
      o_out[(size_t)i*CC + t] = (pa[t] + pa[t+CC]) * inv_sum[h] * gate;
    }
  }
}

// final fused: aout = o_gat@wo + bo;  out = sg_og*aout + sg_tg*(hid @ t_out_w)
__global__ __launch_bounds__(256) void k_final(const float* __restrict__ og,
    const float* __restrict__ wo, const float* __restrict__ bo,
    const float* __restrict__ hid, const float* __restrict__ tw,
    const float* __restrict__ sgog, const float* __restrict__ sgtg,
    float* __restrict__ outp)
{
  __shared__ float As[8*CC];
  __shared__ float Hs[8*256];
  const int row0 = blockIdx.x*8;
  const int t = threadIdx.x;
  const int tr=t>>5, col=(t&31)*4;
  *(float4*)(As+t*4) = *(const float4*)(og + (size_t)(row0+tr)*CC + col);
  {
    const float4* src=(const float4*)(hid + (size_t)row0*256);
    float4* dst=(float4*)Hs;
    dst[t]=src[t]; dst[t+256]=src[t+256];
  }
  __syncthreads();
  float acc0[4]={0,0,0,0}, acc1[4]={0,0,0,0};
  #pragma unroll 4
  for (int k=0;k<256;k++){
    float a=Hs[tr*256+k];
    float4 w=*(const float4*)(tw + (size_t)k*CC + col);
    acc0[0]+=a*w.x; acc0[1]+=a*w.y; acc0[2]+=a*w.z; acc0[3]+=a*w.w;
  }
  #pragma unroll 4
  for (int k=0;k<CC;k++){
    float a=As[tr*CC+k];
    float4 w=*(const float4*)(wo + (size_t)k*CC + col);
    acc1[0]+=a*w.x; acc1[1]+=a*w.y; acc1[2]+=a*w.z; acc1[3]+=a*w.w;
  }
  const size_t off=(size_t)(row0+tr)*CC+col;
  float4 bb=*(const float4*)(bo+col);
  float4 g0=*(const float4*)(sgog+off);
  float4 g1=*(const float4*)(sgtg+off);
  float4 o;
  o.x=g0.x*(acc1[0]+bb.x)+g1.x*acc0[0];
  o.y=g0.y*(acc1[1]+bb.y)+g1.y*acc0[1];
  o.z=g0.z*(acc1[2]+bb.z)+g1.z*acc0[2];
  o.w=g0.w*(acc1[3]+bb.w)+g1.w*acc0[3];
  *(float4*)(outp+off)=o;
}

extern "C" void kernel_launch(void* const* d_in, const int* in_sizes, int n_in,
                              void* d_out, int out_size, void* d_ws, size_t ws_size,
                              hipStream_t stream) {
  const float* a_in = (const float*)d_in[0];
  const float* s_in = (const float*)d_in[1];
  const float* pair = (const float*)d_in[2];
  const float* mask = (const float*)d_in[3];
  const float* adaln_s_scale = (const float*)d_in[4];
  const float* adaln_gate_w  = (const float*)d_in[5];
  const float* adaln_gate_b  = (const float*)d_in[6];
  const float* adaln_skip_w  = (const float*)d_in[7];
  const float* wq = (const float*)d_in[8];
  const float* wk = (const float*)d_in[9];
  const float* wv = (const float*)d_in[10];
  const float* wg = (const float*)d_in[11];
  const float* bg = (const float*)d_in[12];
  const float* wo = (const float*)d_in[13];
  const float* bo = (const float*)d_in[14];
  const float* pls = (const float*)d_in[15];
  const float* plb = (const float*)d_in[16];
  const float* w_pair = (const float*)d_in[17];
  const float* out_gate_w = (const float*)d_in[18];
  const float* out_gate_b = (const float*)d_in[19];
  const float* t_s_scale  = (const float*)d_in[20];
  const float* t_gate_w   = (const float*)d_in[21];
  const float* t_gate_b   = (const float*)d_in[22];
  const float* t_skip_w   = (const float*)d_in[23];
  const float* t_swish_w  = (const float*)d_in[24];
  const float* t_hidden_w = (const float*)d_in[25];
  const float* t_out_w    = (const float*)d_in[26];
  const float* t_out_gate_w = (const float*)d_in[27];
  const float* t_out_gate_b = (const float*)d_in[28];

  float* ws = (float*)d_ws;
  const size_t U = (size_t)NN*CC;
  float* sg_og = ws + 0*U;
  float* sg_tg = ws + 1*U;
  float* a_att = ws + 2*U;
  float* tcond = ws + 3*U;
  float* qb    = ws + 4*U;
  float* kb    = ws + 5*U;
  float* vb    = ws + 6*U;
  float* gg    = ws + 7*U;
  float* o_gat = ws + 8*U;
  float* hid   = ws + 9*U;   // 2 units [NN][256]

  dim3 blk(256);
  k_pre<<<dim3(NN/8,3), blk, 0, stream>>>(a_in, s_in,
      adaln_s_scale, adaln_gate_w, adaln_gate_b, adaln_skip_w,
      t_s_scale, t_gate_w, t_gate_b, t_skip_w,
      out_gate_w, out_gate_b, t_out_gate_w, t_out_gate_b,
      sg_og, sg_tg, a_att, tcond);
  k_mid<<<dim3(NN/16,4), blk, 0, stream>>>(a_att, tcond, wq, wk, wv, wg, bg,
      t_swish_w, t_hidden_w, qb, kb, vb, gg, hid);
  attn_win<<<NN, blk, 0, stream>>>(qb, kb, vb, gg, pair, pls, plb, w_pair, mask, o_gat);
  k_final<<<NN/8, blk, 0, stream>>>(o_gat, wo, bo, hid, t_out_w, sg_og, sg_tg, (float*)d_out);
}

// Round 6
// 512.505 us; speedup vs baseline: 1.2343x; 1.2343x over previous
//
#include <hip/hip_runtime.h>

#define NN 2048
#define CC 128
#define CPC 16
#define HH 8
#define DD 16
#define WHALF 64

__device__ __forceinline__ float sigf(float x){ return 1.0f/(1.0f+__expf(-x)); }

// Core: C[m] = (A*diag(scale)?) @ Wm for up to 2 weight mats sharing A.
// Block covers RPT*8 rows x 128 cols; 256 threads; thread = (tr=t>>5 row slot, tc=t&31 col*4).
template<int K, int RPT, int NM>
__device__ __forceinline__ void gemm_core(const float* __restrict__ Arows,
                                          const float* __restrict__ scale,
                                          const float* __restrict__ W0,
                                          const float* __restrict__ W1,
                                          int ldw, int colBase,
                                          float acc[NM][RPT][4], float* As){
  const int t = threadIdx.x;
  constexpr int ROWS = RPT*8;
  const int nv = ROWS*K/4;
  for (int i=t;i<nv;i+=256){
    float4 v = ((const float4*)Arows)[i];
    if (scale){
      int kk = (i*4)&(K-1);
      v.x*=scale[kk]; v.y*=scale[kk+1]; v.z*=scale[kk+2]; v.w*=scale[kk+3];
    }
    ((float4*)As)[i]=v;
  }
  __syncthreads();
  const int tr = t>>5;
  const int col = colBase + (t&31)*4;
  #pragma unroll
  for(int m=0;m<NM;m++)
    #pragma unroll
    for(int r=0;r<RPT;r++){ acc[m][r][0]=0;acc[m][r][1]=0;acc[m][r][2]=0;acc[m][r][3]=0; }
  #pragma unroll 4
  for (int k=0;k<K;k++){
    float a[RPT];
    #pragma unroll
    for (int r=0;r<RPT;r++) a[r]=As[(tr*RPT+r)*K+k];   // 2-addr broadcast per wave: free
    {
      float4 w = *(const float4*)(W0 + (size_t)k*ldw + col);
      #pragma unroll
      for (int r=0;r<RPT;r++){acc[0][r][0]+=a[r]*w.x;acc[0][r][1]+=a[r]*w.y;acc[0][r][2]+=a[r]*w.z;acc[0][r][3]+=a[r]*w.w;}
    }
    if constexpr (NM>1){
      float4 w = *(const float4*)(W1 + (size_t)k*ldw + col);
      #pragma unroll
      for (int r=0;r<RPT;r++){acc[1][r][0]+=a[r]*w.x;acc[1][r][1]+=a[r]*w.y;acc[1][r][2]+=a[r]*w.z;acc[1][r][3]+=a[r]*w.w;}
    }
  }
}

// Fused pre-attention kernel. blockIdx.y selects:
//  y=0: sg_og = sigmoid(s@og_w+og_b), sg_tg = sigmoid(s@tg_w+tg_b)   (raw s)
//  y=1: a_att = sigmoid(sn@ada_gw+ada_gb)*LN(a) + sn@ada_sw, sn=LN(s)*ada_sc
//  y=2: tcond = same with t_* params
__global__ __launch_bounds__(256) void k_pre(
    const float* __restrict__ a_in, const float* __restrict__ s_in,
    const float* __restrict__ ada_sc, const float* __restrict__ ada_gw,
    const float* __restrict__ ada_gb, const float* __restrict__ ada_sw,
    const float* __restrict__ t_sc, const float* __restrict__ t_gw,
    const float* __restrict__ t_gb, const float* __restrict__ t_sw,
    const float* __restrict__ og_w, const float* __restrict__ og_b,
    const float* __restrict__ tg_w, const float* __restrict__ tg_b,
    float* __restrict__ sg_og, float* __restrict__ sg_tg,
    float* __restrict__ a_att, float* __restrict__ tcond)
{
  __shared__ float As[8*CC];
  __shared__ float Ls[8*CC];
  const int y = blockIdx.y;
  const int row0 = blockIdx.x*8;
  const int t = threadIdx.x;
  const int tr = t>>5, col = (t&31)*4;
  {
    float4 v = *(const float4*)(s_in + (size_t)(row0+tr)*CC + col);
    if (y==0){
      *(float4*)(As + t*4) = v;
    } else {
      float s1 = v.x+v.y+v.z+v.w;
      float s2 = v.x*v.x+v.y*v.y+v.z*v.z+v.w*v.w;
      #pragma unroll
      for (int m=16;m;m>>=1){ s1+=__shfl_xor(s1,m); s2+=__shfl_xor(s2,m); }
      float mean=s1*(1.0f/CC), var=s2*(1.0f/CC)-mean*mean, inv=rsqrtf(var+1e-5f);
      const float* sc = (y==1)? ada_sc : t_sc;
      float4 scv = *(const float4*)(sc+col);
      float4 o; o.x=(v.x-mean)*inv*scv.x; o.y=(v.y-mean)*inv*scv.y;
                o.z=(v.z-mean)*inv*scv.z; o.w=(v.w-mean)*inv*scv.w;
      *(float4*)(As + t*4) = o;
      float4 av = *(const float4*)(a_in + (size_t)(row0+tr)*CC + col);
      float a1 = av.x+av.y+av.z+av.w;
      float a2 = av.x*av.x+av.y*av.y+av.z*av.z+av.w*av.w;
      #pragma unroll
      for (int m=16;m;m>>=1){ a1+=__shfl_xor(a1,m); a2+=__shfl_xor(a2,m); }
      float am=a1*(1.0f/CC), avr=a2*(1.0f/CC)-am*am, ai=rsqrtf(avr+1e-5f);
      float4 la; la.x=(av.x-am)*ai; la.y=(av.y-am)*ai;
                 la.z=(av.z-am)*ai; la.w=(av.w-am)*ai;
      *(float4*)(Ls + t*4) = la;
    }
  }
  __syncthreads();
  const float* W0 = (y==0)? og_w : ((y==1)? ada_gw : t_gw);
  const float* W1 = (y==0)? tg_w : ((y==1)? ada_sw : t_sw);
  float acc0[4]={0,0,0,0}, acc1[4]={0,0,0,0};
  #pragma unroll 4
  for (int k=0;k<CC;k++){
    float a = As[tr*CC+k];
    float4 w0 = *(const float4*)(W0 + (size_t)k*CC + col);
    float4 w1 = *(const float4*)(W1 + (size_t)k*CC + col);
    acc0[0]+=a*w0.x; acc0[1]+=a*w0.y; acc0[2]+=a*w0.z; acc0[3]+=a*w0.w;
    acc1[0]+=a*w1.x; acc1[1]+=a*w1.y; acc1[2]+=a*w1.z; acc1[3]+=a*w1.w;
  }
  const size_t off = (size_t)(row0+tr)*CC + col;
  if (y==0){
    float4 b0 = *(const float4*)(og_b+col);
    float4 b1 = *(const float4*)(tg_b+col);
    float4 o0 = {sigf(acc0[0]+b0.x),sigf(acc0[1]+b0.y),sigf(acc0[2]+b0.z),sigf(acc0[3]+b0.w)};
    float4 o1 = {sigf(acc1[0]+b1.x),sigf(acc1[1]+b1.y),sigf(acc1[2]+b1.z),sigf(acc1[3]+b1.w)};
    *(float4*)(sg_og+off)=o0; *(float4*)(sg_tg+off)=o1;
  } else {
    const float* gbp = (y==1)? ada_gb : t_gb;
    float4 gb = *(const float4*)(gbp+col);
    float4 la = *(const float4*)(Ls + t*4);
    float4 o;
    o.x = sigf(acc0[0]+gb.x)*la.x + acc1[0];
    o.y = sigf(acc0[1]+gb.y)*la.y + acc1[1];
    o.z = sigf(acc0[2]+gb.z)*la.z + acc1[2];
    o.w = sigf(acc0[3]+gb.w)*la.w + acc1[3];
    float* dst = (y==1)? a_att : tcond;
    *(float4*)(dst+off)=o;
  }
}

// q,k (y=0) and v,g (y=1) projections; g gets bias bg (pre-sigmoid store).
__global__ __launch_bounds__(256) void k_qkvg(const float* __restrict__ A,
    const float* __restrict__ wq, const float* __restrict__ wk,
    const float* __restrict__ wv, const float* __restrict__ wg,
    const float* __restrict__ bg,
    float* __restrict__ qb, float* __restrict__ kb,
    float* __restrict__ vb, float* __restrict__ gg){
  __shared__ float As[16*128];
  float acc[2][2][4];
  const int row0 = blockIdx.x*16;
  const int y = blockIdx.y;
  const float* W0 = y ? wv : wq;
  const float* W1 = y ? wg : wk;
  gemm_core<128,2,2>(A + (size_t)row0*CC, nullptr, W0, W1, 128, 0, acc, As);
  const int col = (threadIdx.x&31)*4;
  float* O0 = y ? vb : qb;
  float* O1 = y ? gg : kb;
  float4 b1 = {0,0,0,0};
  if (y) b1 = *(const float4*)(bg+col);
  #pragma unroll
  for (int r=0;r<2;r++){
    const int row = row0 + (threadIdx.x>>5)*2 + r;
    float4 o0 = {acc[0][r][0],acc[0][r][1],acc[0][r][2],acc[0][r][3]};
    float4 o1 = {acc[1][r][0]+b1.x,acc[1][r][1]+b1.y,acc[1][r][2]+b1.z,acc[1][r][3]+b1.w};
    *(float4*)(O0 + (size_t)row*CC + col) = o0;
    *(float4*)(O1 + (size_t)row*CC + col) = o1;
  }
}

// hid[:, y*128+col] = silu(t@swish) * (t@hidden); ldw=256.
__global__ __launch_bounds__(256) void k_swiglu(const float* __restrict__ A,
    const float* __restrict__ sw_w, const float* __restrict__ hd_w,
    float* __restrict__ hid)
{
  __shared__ float As[8*CC];
  const int row0 = blockIdx.x*8;
  const int cb = blockIdx.y*128;
  const int t = threadIdx.x;
  const int tr=t>>5, c32=(t&31)*4;
  *(float4*)(As+t*4) = *(const float4*)(A + (size_t)(row0+tr)*CC + c32);
  __syncthreads();
  const int col = cb + c32;
  float a0[4]={0,0,0,0}, a1[4]={0,0,0,0};
  #pragma unroll 4
  for (int k=0;k<CC;k++){
    float a=As[tr*CC+k];
    float4 w0=*(const float4*)(sw_w + (size_t)k*256 + col);
    float4 w1=*(const float4*)(hd_w + (size_t)k*256 + col);
    a0[0]+=a*w0.x; a0[1]+=a*w0.y; a0[2]+=a*w0.z; a0[3]+=a*w0.w;
    a1[0]+=a*w1.x; a1[1]+=a*w1.y; a1[2]+=a*w1.z; a1[3]+=a*w1.w;
  }
  float4 o;
  o.x=a0[0]*sigf(a0[0])*a1[0];
  o.y=a0[1]*sigf(a0[1])*a1[1];
  o.z=a0[2]*sigf(a0[2])*a1[2];
  o.w=a0[3]*sigf(a0[3])*a1[3];
  *(float4*)(hid + (size_t)(row0+tr)*256 + col) = o;
}

// Windowed attention with pair bias. One block per query row i. 256 threads.
// Score/softmax phases as proven baseline; PV phase 2-way j-split + LDS combine.
__global__ __launch_bounds__(256) void attn_win(const float* __restrict__ q,
    const float* __restrict__ k, const float* __restrict__ v,
    const float* __restrict__ g, const float* __restrict__ pair,
    const float* __restrict__ pls, const float* __restrict__ plb,
    const float* __restrict__ w_pair, const float* __restrict__ mask,
    float* __restrict__ o_out) {
  __shared__ __align__(16) float qs[CC];
  __shared__ float sc[HH][132];
  __shared__ float wp[CPC][HH];
  __shared__ float plss[CPC], plbs[CPC];
  __shared__ float inv_sum[HH];
  __shared__ float pa[256];
  const int i = blockIdx.x;
  const int t = threadIdx.x;
  if (t < CC) qs[t] = q[(size_t)i*CC + t] * 0.25f;   // D^-0.5 = 1/4
  if (t < CPC*HH) wp[t>>3][t&7] = w_pair[t];         // [CP][H] row-major
  if (t >= 128 && t < 128+CPC){ plss[t-128]=pls[t-128]; plbs[t-128]=plb[t-128]; }
  __syncthreads();
  const int jlo = (i-WHALF > 0) ? i-WHALF : 0;
  const int jhi = (i+WHALF < NN-1) ? i+WHALF : NN-1;
  const int nj = jhi - jlo + 1;      // 65..129
  if (t < nj){
    const int j = jlo + t;
    float pv[CPC]; float s=0.f, sq=0.f;
    const float4* pp4 = (const float4*)(pair + ((size_t)i*NN + j)*CPC);
    #pragma unroll
    for (int c4=0;c4<CPC/4;c4++){
      float4 x4 = pp4[c4];
      pv[c4*4]=x4.x; pv[c4*4+1]=x4.y; pv[c4*4+2]=x4.z; pv[c4*4+3]=x4.w;
      s += x4.x+x4.y+x4.z+x4.w;
      sq += x4.x*x4.x+x4.y*x4.y+x4.z*x4.z+x4.w*x4.w;
    }
    float mean = s*(1.0f/CPC);
    float var  = sq*(1.0f/CPC)-mean*mean;
    float inv  = rsqrtf(var+1e-5f);
    #pragma unroll
    for (int c=0;c<CPC;c++) pv[c] = (pv[c]-mean)*inv*plss[c] + plbs[c];
    float mterm = 1e9f*(mask[j]-1.0f);
    const float4* kr4 = (const float4*)(k + (size_t)j*CC);
    const float4* qs4 = (const float4*)qs;
    #pragma unroll
    for (int h=0;h<HH;h++){
      float bias = 0.f;
      #pragma unroll
      for (int c=0;c<CPC;c++) bias += pv[c]*wp[c][h];
      float d = 0.f;
      #pragma unroll
      for (int w=0;w<4;w++){
        float4 kk = kr4[h*4+w];
        float4 qq = qs4[h*4+w];
        d += kk.x*qq.x + kk.y*qq.y + kk.z*qq.z + kk.w*qq.w;
      }
      sc[h][t] = d + bias + mterm;
    }
  }
  __syncthreads();
  { // per-head softmax: 8 groups of 32 lanes
    const int h = t >> 5;
    const int l = t & 31;
    float m = -1e30f;
    for (int jj=l; jj<nj; jj+=32) m = fmaxf(m, sc[h][jj]);
    #pragma unroll
    for (int mm=16;mm;mm>>=1) m = fmaxf(m, __shfl_xor(m,mm));
    float ss = 0.f;
    for (int jj=l; jj<nj; jj+=32){ float e=__expf(sc[h][jj]-m); sc[h][jj]=e; ss+=e; }
    #pragma unroll
    for (int mm=16;mm;mm>>=1) ss += __shfl_xor(ss,mm);
    if (l==0) inv_sum[h] = 1.0f/ss;
  }
  __syncthreads();
  { // PV: thread -> (col c, j-half), then combine halves through LDS
    const int c = t & 127, half = t>>7;
    const int h = c >> 4;
    float acc = 0.f;
    for (int jj=half; jj<nj; jj+=2)
      acc += sc[h][jj] * v[(size_t)(jlo+jj)*CC + c];
    pa[t] = acc;
    __syncthreads();
    if (t < CC){
      float gate = sigf(g[(size_t)i*CC + t]);
      o_out[(size_t)i*CC + t] = (pa[t] + pa[t+CC]) * inv_sum[h] * gate;
    }
  }
}

// final fused: aout = o_gat@wo + bo;  out = sg_og*aout + sg_tg*(hid @ t_out_w)
__global__ __launch_bounds__(256) void k_final(const float* __restrict__ og,
    const float* __restrict__ wo, const float* __restrict__ bo,
    const float* __restrict__ hid, const float* __restrict__ tw,
    const float* __restrict__ sgog, const float* __restrict__ sgtg,
    float* __restrict__ outp)
{
  __shared__ float As[8*CC];
  __shared__ float Hs[8*256];
  const int row0 = blockIdx.x*8;
  const int t = threadIdx.x;
  const int tr=t>>5, col=(t&31)*4;
  *(float4*)(As+t*4) = *(const float4*)(og + (size_t)(row0+tr)*CC + col);
  {
    const float4* src=(const float4*)(hid + (size_t)row0*256);
    float4* dst=(float4*)Hs;
    dst[t]=src[t]; dst[t+256]=src[t+256];
  }
  __syncthreads();
  float acc0[4]={0,0,0,0}, acc1[4]={0,0,0,0};
  #pragma unroll 4
  for (int k=0;k<256;k++){
    float a=Hs[tr*256+k];
    float4 w=*(const float4*)(tw + (size_t)k*CC + col);
    acc0[0]+=a*w.x; acc0[1]+=a*w.y; acc0[2]+=a*w.z; acc0[3]+=a*w.w;
  }
  #pragma unroll 4
  for (int k=0;k<CC;k++){
    float a=As[tr*CC+k];
    float4 w=*(const float4*)(wo + (size_t)k*CC + col);
    acc1[0]+=a*w.x; acc1[1]+=a*w.y; acc1[2]+=a*w.z; acc1[3]+=a*w.w;
  }
  const size_t off=(size_t)(row0+tr)*CC+col;
  float4 bb=*(const float4*)(bo+col);
  float4 g0=*(const float4*)(sgog+off);
  float4 g1=*(const float4*)(sgtg+off);
  float4 o;
  o.x=g0.x*(acc1[0]+bb.x)+g1.x*acc0[0];
  o.y=g0.y*(acc1[1]+bb.y)+g1.y*acc0[1];
  o.z=g0.z*(acc1[2]+bb.z)+g1.z*acc0[2];
  o.w=g0.w*(acc1[3]+bb.w)+g1.w*acc0[3];
  *(float4*)(outp+off)=o;
}

extern "C" void kernel_launch(void* const* d_in, const int* in_sizes, int n_in,
                              void* d_out, int out_size, void* d_ws, size_t ws_size,
                              hipStream_t stream) {
  const float* a_in = (const float*)d_in[0];
  const float* s_in = (const float*)d_in[1];
  const float* pair = (const float*)d_in[2];
  const float* mask = (const float*)d_in[3];
  const float* adaln_s_scale = (const float*)d_in[4];
  const float* adaln_gate_w  = (const float*)d_in[5];
  const float* adaln_gate_b  = (const float*)d_in[6];
  const float* adaln_skip_w  = (const float*)d_in[7];
  const float* wq = (const float*)d_in[8];
  const float* wk = (const float*)d_in[9];
  const float* wv = (const float*)d_in[10];
  const float* wg = (const float*)d_in[11];
  const float* bg = (const float*)d_in[12];
  const float* wo = (const float*)d_in[13];
  const float* bo = (const float*)d_in[14];
  const float* pls = (const float*)d_in[15];
  const float* plb = (const float*)d_in[16];
  const float* w_pair = (const float*)d_in[17];
  const float* out_gate_w = (const float*)d_in[18];
  const float* out_gate_b = (const float*)d_in[19];
  const float* t_s_scale  = (const float*)d_in[20];
  const float* t_gate_w   = (const float*)d_in[21];
  const float* t_gate_b   = (const float*)d_in[22];
  const float* t_skip_w   = (const float*)d_in[23];
  const float* t_swish_w  = (const float*)d_in[24];
  const float* t_hidden_w = (const float*)d_in[25];
  const float* t_out_w    = (const float*)d_in[26];
  const float* t_out_gate_w = (const float*)d_in[27];
  const float* t_out_gate_b = (const float*)d_in[28];

  float* ws = (float*)d_ws;
  const size_t U = (size_t)NN*CC;
  float* sg_og = ws + 0*U;
  float* sg_tg = ws + 1*U;
  float* a_att = ws + 2*U;
  float* tcond = ws + 3*U;
  float* qb    = ws + 4*U;
  float* kb    = ws + 5*U;
  float* vb    = ws + 6*U;
  float* gg    = ws + 7*U;
  float* o_gat = ws + 8*U;
  float* hid   = ws + 9*U;   // 2 units [NN][256]

  dim3 blk(256);
  k_pre<<<dim3(NN/8,3), blk, 0, stream>>>(a_in, s_in,
      adaln_s_scale, adaln_gate_w, adaln_gate_b, adaln_skip_w,
      t_s_scale, t_gate_w, t_gate_b, t_skip_w,
      out_gate_w, out_gate_b, t_out_gate_w, t_out_gate_b,
      sg_og, sg_tg, a_att, tcond);
  k_qkvg<<<dim3(NN/16,2), blk, 0, stream>>>(a_att, wq, wk, wv, wg, bg, qb, kb, vb, gg);
  k_swiglu<<<dim3(NN/8,2), blk, 0, stream>>>(tcond, t_swish_w, t_hidden_w, hid);
  attn_win<<<NN, blk, 0, stream>>>(qb, kb, vb, gg, pair, pls, plb, w_pair, mask, o_gat);
  k_final<<<NN/8, blk, 0, stream>>>(o_gat, wo, bo, hid, t_out_w, sg_og, sg_tg, (float*)d_out);
}